// Round 20
// baseline (240.264 us; speedup 1.0000x reference)
//
#include <hip/hip_runtime.h>
#include <hip/hip_bf16.h>

#define NN 100000
#define EE 800000
#define GG 1024
#define PREPB 69    // blocks doing precompute work inside k_zero_prep
#define NEB 1563    // edge blocks (hist-scatter, 2 edges/thread)

typedef __attribute__((ext_vector_type(8))) short short8;
typedef __attribute__((ext_vector_type(4))) float floatx4;
typedef __attribute__((ext_vector_type(2))) float floatx2;

__device__ __forceinline__ float sigmoidf_(float v) { return 1.f / (1.f + expf(-v)); }
__device__ __forceinline__ unsigned short f2bf(float f) {
    union { unsigned int i; float f; } x; x.f = f;
    unsigned int r = (x.i + 0x7fff + ((x.i >> 16) & 1)) >> 16;
    return (unsigned short)r;
}
__device__ __forceinline__ unsigned pack2bf(float a, float b) {
    return (unsigned)f2bf(a) | ((unsigned)f2bf(b) << 16);
}
__device__ __forceinline__ float lrelu(float e) { return (e > 0.f) ? e : 0.2f * e; }

// ---- fused init + precompute; also plants self-loop in bucket slot 0 ----
__global__ void k_zero_prep(const float* __restrict__ e0, const float* __restrict__ e1,
                            const float* __restrict__ e2, const float* __restrict__ e3,
                            const float* __restrict__ e4, const float* __restrict__ e5,
                            const float* __restrict__ W1, const float* __restrict__ W2,
                            const float* __restrict__ b1, const float* __restrict__ b2,
                            const float* __restrict__ lw,
                            const float* __restrict__ as1, const float* __restrict__ ad1,
                            unsigned short* __restrict__ Wt2,
                            float* __restrict__ b1p, float* __restrict__ b2p,
                            float* __restrict__ lwp,
                            float* __restrict__ asvp, float* __restrict__ advp,
                            float* __restrict__ Pp,
                            int* __restrict__ cnt, int* __restrict__ csrc,
                            float* __restrict__ gsum) {
    int i = blockIdx.x * 256 + threadIdx.x;
    if (i < NN) {
        cnt[i] = 1;                    // slot 0 reserved for self-loop
        csrc[(size_t)i << 6] = i;      // self-loop
    }
    if (i < GG * 64) gsum[i] = 0.f;
    if (blockIdx.x >= PREPB) return;
    if (i < 4096) {
        int tid = i;
        int l = tid & 63, cf = (tid >> 6) & 15, ks = tid >> 10;
        int kbase = ks * 32 + (l >> 4) * 8;
        int col = cf * 16 + (l & 15);
        unsigned short* o = Wt2 + (size_t)tid * 8;
#pragma unroll
        for (int j = 0; j < 8; j++) {
            int k = kbase + j;   // k in h1-permuted space
            int orig = (k & 64) | (((k & 3) * 16) + ((k & 63) >> 2));
            o[j] = f2bf(W2[(size_t)orig * 256 + col]);
        }
    } else if (i < 4096 + 128) {
        int q = i - 4096;
        int orig = (q & 64) | (((q & 3) * 16) + ((q & 63) >> 2));
        b1p[q] = b1[orig];
    } else if (i < 4224 + 64) {
        int q = i - 4224;
        b2p[q] = b2[(q & 3) * 16 + (q >> 2)];
    } else if (i < 4288 + 64) {
        int q = i - 4288;
        lwp[q] = lw[(q & 3) * 16 + (q >> 2)];
    } else if (i < 4352 + 256) {
        int q = i - 4352;
        int c = (q >> 6) * 64 + (q & 3) * 16 + ((q >> 2) & 15);
        asvp[q] = as1[c];
    } else if (i < 4608 + 256) {
        int q = i - 4608;
        int c = (q >> 6) * 64 + (q & 3) * 16 + ((q >> 2) & 15);
        advp[q] = ad1[c];
    } else if (i < 4864 + 12800) {
        int idx = i - 4864;
        int v = idx >> 8, p = idx & 255;
        int t, r;
        const float* tab;
        if (v < 33)      { t = 0; r = v;      tab = e0; }
        else if (v < 38) { t = 1; r = v - 33; tab = e1; }
        else if (v < 41) { t = 2; r = v - 38; tab = e2; }
        else if (v < 45) { t = 3; r = v - 41; tab = e3; }
        else if (v < 47) { t = 4; r = v - 45; tab = e4; }
        else             { t = 5; r = v - 47; tab = e5; }
        int c = (p >> 6) * 64 + (p & 3) * 16 + ((p >> 2) & 15);
        float acc = 0.f;
        const float* wcol = W1 + (size_t)(t * 64) * 256 + c;
#pragma unroll 8
        for (int kk = 0; kk < 64; kk++) acc += tab[r * 64 + kk] * wcol[(size_t)kk * 256];
        Pp[v * 256 + p] = acc;
    }
}

// ---- fused hist-scatter (blocks < NEB, 2 edges/thread) + layer-1 table GEMM ----
// xw1: 32 lanes per node, 8 nodes per block
__global__ __launch_bounds__(256) void k_histscat_xw1(const int* __restrict__ ei,
                                                      int* __restrict__ cnt,
                                                      int* __restrict__ csrc,
                                                      const int* __restrict__ x,
                                                      const float* __restrict__ Pp,
                                                      const float* __restrict__ asvp,
                                                      const float* __restrict__ advp,
                                                      unsigned int* __restrict__ C32,
                                                      float* __restrict__ s1,
                                                      float* __restrict__ d1) {
    if (blockIdx.x < NEB) {
        int e0_ = blockIdx.x * 512 + threadIdx.x;
        int e1_ = e0_ + 256;
        if (e0_ < EE) {
            int s = ei[e0_], d = ei[EE + e0_];
            int p = atomicAdd(&cnt[d], 1);
            csrc[((size_t)d << 6) + p] = s;
        }
        if (e1_ < EE) {
            int s = ei[e1_], d = ei[EE + e1_];
            int p = atomicAdd(&cnt[d], 1);
            csrc[((size_t)d << 6) + p] = s;
        }
        return;
    }
    int g = threadIdx.x >> 5, l = threadIdx.x & 31;
    int n = (blockIdx.x - NEB) * 8 + g;
    const int2* xr = (const int2*)(x + n * 6);
    int2 xa = xr[0], xb = xr[1], xc = xr[2];
    int v0 = xa.x, v1 = 33 + xa.y, v2 = 38 + xb.x;
    int v3 = 41 + xb.y, v4 = 45 + xc.x, v5 = 47 + xc.y;
    float4 accA = make_float4(0.f, 0.f, 0.f, 0.f);
    float4 accB = make_float4(0.f, 0.f, 0.f, 0.f);
    {
        const float* p0 = Pp + v0 * 256 + l * 8;
        const float* p1 = Pp + v1 * 256 + l * 8;
        const float* p2 = Pp + v2 * 256 + l * 8;
        const float* p3 = Pp + v3 * 256 + l * 8;
        const float* p4 = Pp + v4 * 256 + l * 8;
        const float* p5 = Pp + v5 * 256 + l * 8;
        float4 a0 = *(const float4*)p0, b0 = *(const float4*)(p0 + 4);
        float4 a1 = *(const float4*)p1, b1_ = *(const float4*)(p1 + 4);
        float4 a2 = *(const float4*)p2, b2_ = *(const float4*)(p2 + 4);
        float4 a3 = *(const float4*)p3, b3 = *(const float4*)(p3 + 4);
        float4 a4 = *(const float4*)p4, b4 = *(const float4*)(p4 + 4);
        float4 a5 = *(const float4*)p5, b5 = *(const float4*)(p5 + 4);
        accA.x = a0.x + a1.x + a2.x + a3.x + a4.x + a5.x;
        accA.y = a0.y + a1.y + a2.y + a3.y + a4.y + a5.y;
        accA.z = a0.z + a1.z + a2.z + a3.z + a4.z + a5.z;
        accA.w = a0.w + a1.w + a2.w + a3.w + a4.w + a5.w;
        accB.x = b0.x + b1_.x + b2_.x + b3.x + b4.x + b5.x;
        accB.y = b0.y + b1_.y + b2_.y + b3.y + b4.y + b5.y;
        accB.z = b0.z + b1_.z + b2_.z + b3.z + b4.z + b5.z;
        accB.w = b0.w + b1_.w + b2_.w + b3.w + b4.w + b5.w;
    }
    float4 sA = *(const float4*)(asvp + l * 8), sB = *(const float4*)(asvp + l * 8 + 4);
    float4 dA = *(const float4*)(advp + l * 8), dB = *(const float4*)(advp + l * 8 + 4);
    float ss = accA.x * sA.x + accA.y * sA.y + accA.z * sA.z + accA.w * sA.w
             + accB.x * sB.x + accB.y * sB.y + accB.z * sB.z + accB.w * sB.w;
    float dd = accA.x * dA.x + accA.y * dA.y + accA.z * dA.z + accA.w * dA.w
             + accB.x * dB.x + accB.y * dB.y + accB.z * dB.z + accB.w * dB.w;
#pragma unroll
    for (int o = 1; o <= 8; o <<= 1) {
        ss += __shfl_xor(ss, o);
        dd += __shfl_xor(dd, o);
    }
    if ((l & 15) == 0) {
        int h = l >> 4;
        s1[n * 2 + h] = ss;
        d1[n * 2 + h] = dd;
    }
    int lo0 = __builtin_amdgcn_cvt_pk_fp8_f32(accA.x, accA.y, 0, false);
    unsigned dw0 = (unsigned)__builtin_amdgcn_cvt_pk_fp8_f32(accA.z, accA.w, lo0, true);
    int lo1 = __builtin_amdgcn_cvt_pk_fp8_f32(accB.x, accB.y, 0, false);
    unsigned dw1 = (unsigned)__builtin_amdgcn_cvt_pk_fp8_f32(accB.z, accB.w, lo1, true);
    *(uint2*)(C32 + (size_t)n * 64 + l * 2) = make_uint2(dw0, dw1);
}

// ------- layer-2 bf16 MFMA GEMM -> fp8 (permuted dword stores) + plain s/d ----
__global__ __launch_bounds__(256) void k_gemm2(const unsigned short* __restrict__ Abf,
                                               const unsigned short* __restrict__ Wt,
                                               unsigned int* __restrict__ C32,
                                               const float* __restrict__ asv,
                                               const float* __restrict__ adv,
                                               float* __restrict__ sOut,
                                               float* __restrict__ dOut, int M) {
    __shared__ __align__(16) unsigned short As[128 * 40];
    __shared__ __align__(16) unsigned short Bs[4 * 64 * 8];
    int tid = threadIdx.x;
    int rowBase = blockIdx.y * 128;
    int colBase = blockIdx.x * 64;
    int l = tid & 63, w = tid >> 6;
    int strip = w * 32;
    floatx4 acc[2][4] = {};

    for (int ks = 0; ks < 4; ks++) {
        {
            int r = tid >> 1, half = tid & 1;
            int row = rowBase + r;
            uint4 v0 = {0, 0, 0, 0}, v1 = {0, 0, 0, 0};
            if (row < M) {
                const unsigned short* src = Abf + (size_t)row * 128 + ks * 32 + half * 16;
                v0 = *(const uint4*)src;
                v1 = *(const uint4*)(src + 8);
            }
            uint4* dst = (uint4*)&As[r * 40 + half * 16];
            dst[0] = v0; dst[1] = v1;
        }
        {
            const unsigned short* wsrc =
                Wt + ((size_t)(ks * 16 + (colBase >> 4)) * 64) * 8 + tid * 8;
            *(uint4*)&Bs[tid * 8] = *(const uint4*)wsrc;
        }
        __syncthreads();
        short8 a0 = *(const short8*)&As[(strip + (l & 15)) * 40 + (l >> 4) * 8];
        short8 a1 = *(const short8*)&As[(strip + 16 + (l & 15)) * 40 + (l >> 4) * 8];
        const short8* bp = (const short8*)&Bs[0];
#pragma unroll
        for (int cf = 0; cf < 4; cf++) {
            short8 b = bp[cf * 64 + l];
            acc[0][cf] = __builtin_amdgcn_mfma_f32_16x16x32_bf16(a0, b, acc[0][cf], 0, 0, 0);
            acc[1][cf] = __builtin_amdgcn_mfma_f32_16x16x32_bf16(a1, b, acc[1][cf], 0, 0, 0);
        }
        __syncthreads();
    }
    float as_[4], ad_[4];
#pragma unroll
    for (int cf = 0; cf < 4; cf++) {
        int col = colBase + cf * 16 + (l & 15);
        as_[cf] = asv[col];
        ad_[cf] = adv[col];
    }
    float ps[8], pd[8];
    unsigned dw[8];
#pragma unroll
    for (int rf = 0; rf < 2; rf++)
#pragma unroll
        for (int i = 0; i < 4; i++) {
            int idx = rf * 4 + i;
            float a0 = acc[rf][0][i], a1 = acc[rf][1][i];
            float a2 = acc[rf][2][i], a3 = acc[rf][3][i];
            ps[idx] = a0 * as_[0] + a1 * as_[1] + a2 * as_[2] + a3 * as_[3];
            pd[idx] = a0 * ad_[0] + a1 * ad_[1] + a2 * ad_[2] + a3 * ad_[3];
            int lo = __builtin_amdgcn_cvt_pk_fp8_f32(a0, a1, 0, false);
            dw[idx] = (unsigned)__builtin_amdgcn_cvt_pk_fp8_f32(a2, a3, lo, true);
        }
#pragma unroll
    for (int rf = 0; rf < 2; rf++)
#pragma unroll
        for (int i = 0; i < 4; i++) {
            int row = rowBase + strip + rf * 16 + (l >> 4) * 4 + i;
            if (row < M) C32[(size_t)row * 64 + (colBase >> 2) + (l & 15)] = dw[rf * 4 + i];
        }
#pragma unroll
    for (int k = 0; k < 8; k++)
#pragma unroll
        for (int o = 8; o; o >>= 1) {
            ps[k] += __shfl_xor(ps[k], o);
            pd[k] += __shfl_xor(pd[k], o);
        }
    if ((l & 15) == 0) {
        int head = colBase >> 6;   // H=4, one block.x per head -> plain store
#pragma unroll
        for (int rf = 0; rf < 2; rf++)
#pragma unroll
            for (int i = 0; i < 4; i++) {
                int row = rowBase + strip + rf * 16 + (l >> 4) * 4 + i;
                if (row < M) {
                    sOut[row * 4 + head] = ps[rf * 4 + i];
                    dOut[row * 4 + head] = pd[rf * 4 + i];
                }
            }
    }
}

// ------- layer-1 aggregation: bucket CSR, no-max softmax, deferred denom -------
__global__ __launch_bounds__(256) void k_agg1(const unsigned char* __restrict__ xw8,
                                              const float* __restrict__ s,
                                              const float* __restrict__ dvec,
                                              const int* __restrict__ cnt,
                                              const int* __restrict__ csrc,
                                              const float* __restrict__ b1p,
                                              unsigned short* __restrict__ h1b) {
    __shared__ int snS[4][4][16];
    __shared__ float wS[4][4][2][16];
    int wv = threadIdx.x >> 6, lane = threadIdx.x & 63;
    int q = lane >> 4, l = lane & 15;
    int hh = l >> 3;
    int n = blockIdx.x * 16 + wv * 4 + q;
    int start = n << 6;
    int deg = cnt[n];
    float2 dn = *(const float2*)(dvec + n * 2);
    floatx2 acc[8] = {};
    float ws0, ws1;

    auto macc = [&](const uint4& v, float wgt) {
        floatx2 p;
        p = __builtin_amdgcn_cvt_pk_f32_fp8(v.x, false); acc[0] += wgt * p;
        p = __builtin_amdgcn_cvt_pk_f32_fp8(v.x, true);  acc[1] += wgt * p;
        p = __builtin_amdgcn_cvt_pk_f32_fp8(v.y, false); acc[2] += wgt * p;
        p = __builtin_amdgcn_cvt_pk_f32_fp8(v.y, true);  acc[3] += wgt * p;
        p = __builtin_amdgcn_cvt_pk_f32_fp8(v.z, false); acc[4] += wgt * p;
        p = __builtin_amdgcn_cvt_pk_f32_fp8(v.z, true);  acc[5] += wgt * p;
        p = __builtin_amdgcn_cvt_pk_f32_fp8(v.w, false); acc[6] += wgt * p;
        p = __builtin_amdgcn_cvt_pk_f32_fp8(v.w, true);  acc[7] += wgt * p;
    };
    auto run_chunk = [&](int cnt_) {
        int j = 0;
        for (; j + 2 <= cnt_; j += 2) {
            int sa = snS[wv][q][j], sb = snS[wv][q][j + 1];
            uint4 va = *(const uint4*)(xw8 + (size_t)sa * 256 + l * 16);
            uint4 vb = *(const uint4*)(xw8 + (size_t)sb * 256 + l * 16);
            float wa = wS[wv][q][hh][j], wb = wS[wv][q][hh][j + 1];
            macc(va, wa); macc(vb, wb);
        }
        if (j < cnt_) {
            int sa = snS[wv][q][j];
            uint4 va = *(const uint4*)(xw8 + (size_t)sa * 256 + l * 16);
            macc(va, wS[wv][q][hh][j]);
        }
    };

    if (deg <= 16) {
        int sn = 0; float w0 = 0.f, w1 = 0.f;
        if (l < deg) {
            sn = csrc[start + l];
            float2 sv = *(const float2*)(s + sn * 2);
            w0 = __expf(lrelu(sv.x + dn.x));
            w1 = __expf(lrelu(sv.y + dn.y));
        }
        snS[wv][q][l] = sn; wS[wv][q][0][l] = w0; wS[wv][q][1][l] = w1;
        run_chunk(deg);
        ws0 = w0; ws1 = w1;
#pragma unroll
        for (int o = 8; o; o >>= 1) {
            ws0 += __shfl_xor(ws0, o);
            ws1 += __shfl_xor(ws1, o);
        }
    } else {
        float wa0 = 0.f, wa1 = 0.f;
        int end = start + deg;
        for (int cb = start; cb < end; cb += 16) {
            int cnt_ = min(16, end - cb);
            int sn = 0; float w0 = 0.f, w1 = 0.f;
            if (l < cnt_) {
                sn = csrc[cb + l];
                float2 sv = *(const float2*)(s + sn * 2);
                w0 = __expf(lrelu(sv.x + dn.x));
                w1 = __expf(lrelu(sv.y + dn.y));
            }
            wa0 += w0; wa1 += w1;
            snS[wv][q][l] = sn; wS[wv][q][0][l] = w0; wS[wv][q][1][l] = w1;
            run_chunk(cnt_);
        }
        ws0 = wa0; ws1 = wa1;
#pragma unroll
        for (int o = 8; o; o >>= 1) {
            ws0 += __shfl_xor(ws0, o);
            ws1 += __shfl_xor(ws1, o);
        }
    }
    float inv = 1.f / ((hh ? ws1 : ws0) + 1e-16f);
    float* af = (float*)acc;
    float hm[16];
#pragma unroll
    for (int k = 0; k < 16; k++) {
        af[k] *= inv;
        hm[k] = 0.5f * (af[k] + __shfl_xor(af[k], 8));  // head mean
    }
    if (l < 8) {
        const float* bb = b1p + l * 16;
        unsigned st[8];
#pragma unroll
        for (int k2 = 0; k2 < 8; k2++)
            st[k2] = pack2bf(sigmoidf_(hm[2 * k2] + bb[2 * k2]),
                             sigmoidf_(hm[2 * k2 + 1] + bb[2 * k2 + 1]));
        uint4* dst = (uint4*)(h1b + (size_t)n * 128 + l * 16);
        dst[0] = make_uint4(st[0], st[1], st[2], st[3]);
        dst[1] = make_uint4(st[4], st[5], st[6], st[7]);
    }
}

// ------- layer-2 aggregation: bucket CSR + run-pooled graph atomics -------
__global__ __launch_bounds__(256) void k_agg2(const unsigned char* __restrict__ xw8,
                                              const float* __restrict__ s,
                                              const float* __restrict__ dvec,
                                              const int* __restrict__ cnt,
                                              const int* __restrict__ csrc,
                                              const float* __restrict__ b2p,
                                              const int* __restrict__ batch,
                                              float* __restrict__ gsum) {
    __shared__ int snS[4][4][16];
    __shared__ float wS[4][4][4][16];
    __shared__ float fsS[16][64];
    __shared__ int batchS[16];
    int wv = threadIdx.x >> 6, lane = threadIdx.x & 63;
    int q = lane >> 4, l = lane & 15;
    int hh = l >> 2;
    int n = blockIdx.x * 16 + wv * 4 + q;
    if (threadIdx.x < 16) batchS[threadIdx.x] = batch[blockIdx.x * 16 + threadIdx.x];
    int start = n << 6;
    int deg = cnt[n];
    float4 dn = *(const float4*)(dvec + n * 4);
    floatx2 acc[8] = {};
    float ws0, ws1, ws2, ws3;

    auto macc = [&](const uint4& v, float wgt) {
        floatx2 p;
        p = __builtin_amdgcn_cvt_pk_f32_fp8(v.x, false); acc[0] += wgt * p;
        p = __builtin_amdgcn_cvt_pk_f32_fp8(v.x, true);  acc[1] += wgt * p;
        p = __builtin_amdgcn_cvt_pk_f32_fp8(v.y, false); acc[2] += wgt * p;
        p = __builtin_amdgcn_cvt_pk_f32_fp8(v.y, true);  acc[3] += wgt * p;
        p = __builtin_amdgcn_cvt_pk_f32_fp8(v.z, false); acc[4] += wgt * p;
        p = __builtin_amdgcn_cvt_pk_f32_fp8(v.z, true);  acc[5] += wgt * p;
        p = __builtin_amdgcn_cvt_pk_f32_fp8(v.w, false); acc[6] += wgt * p;
        p = __builtin_amdgcn_cvt_pk_f32_fp8(v.w, true);  acc[7] += wgt * p;
    };
    auto run_chunk = [&](int cnt_) {
        int j = 0;
        for (; j + 2 <= cnt_; j += 2) {
            int sa = snS[wv][q][j], sb = snS[wv][q][j + 1];
            uint4 va = *(const uint4*)(xw8 + (size_t)sa * 256 + l * 16);
            uint4 vb = *(const uint4*)(xw8 + (size_t)sb * 256 + l * 16);
            float wa = wS[wv][q][hh][j], wb = wS[wv][q][hh][j + 1];
            macc(va, wa); macc(vb, wb);
        }
        if (j < cnt_) {
            int sa = snS[wv][q][j];
            uint4 va = *(const uint4*)(xw8 + (size_t)sa * 256 + l * 16);
            macc(va, wS[wv][q][hh][j]);
        }
    };

    if (deg <= 16) {
        int sn = 0;
        float w0 = 0.f, w1 = 0.f, w2 = 0.f, w3 = 0.f;
        if (l < deg) {
            sn = csrc[start + l];
            float4 sv = *(const float4*)(s + sn * 4);
            w0 = __expf(lrelu(sv.x + dn.x));
            w1 = __expf(lrelu(sv.y + dn.y));
            w2 = __expf(lrelu(sv.z + dn.z));
            w3 = __expf(lrelu(sv.w + dn.w));
        }
        snS[wv][q][l] = sn;
        wS[wv][q][0][l] = w0; wS[wv][q][1][l] = w1;
        wS[wv][q][2][l] = w2; wS[wv][q][3][l] = w3;
        run_chunk(deg);
        ws0 = w0; ws1 = w1; ws2 = w2; ws3 = w3;
#pragma unroll
        for (int o = 8; o; o >>= 1) {
            ws0 += __shfl_xor(ws0, o); ws1 += __shfl_xor(ws1, o);
            ws2 += __shfl_xor(ws2, o); ws3 += __shfl_xor(ws3, o);
        }
    } else {
        float wa0 = 0.f, wa1 = 0.f, wa2 = 0.f, wa3 = 0.f;
        int end = start + deg;
        for (int cb = start; cb < end; cb += 16) {
            int cnt_ = min(16, end - cb);
            int sn = 0; float w0 = 0.f, w1 = 0.f, w2 = 0.f, w3 = 0.f;
            if (l < cnt_) {
                sn = csrc[cb + l];
                float4 sv = *(const float4*)(s + sn * 4);
                w0 = __expf(lrelu(sv.x + dn.x));
                w1 = __expf(lrelu(sv.y + dn.y));
                w2 = __expf(lrelu(sv.z + dn.z));
                w3 = __expf(lrelu(sv.w + dn.w));
            }
            wa0 += w0; wa1 += w1; wa2 += w2; wa3 += w3;
            snS[wv][q][l] = sn;
            wS[wv][q][0][l] = w0; wS[wv][q][1][l] = w1;
            wS[wv][q][2][l] = w2; wS[wv][q][3][l] = w3;
            run_chunk(cnt_);
        }
        ws0 = wa0; ws1 = wa1; ws2 = wa2; ws3 = wa3;
#pragma unroll
        for (int o = 8; o; o >>= 1) {
            ws0 += __shfl_xor(ws0, o); ws1 += __shfl_xor(ws1, o);
            ws2 += __shfl_xor(ws2, o); ws3 += __shfl_xor(ws3, o);
        }
    }
    float wsel = (hh & 2) ? ((hh & 1) ? ws3 : ws2) : ((hh & 1) ? ws1 : ws0);
    float inv = 1.f / (wsel + 1e-16f);
    float* af = (float*)acc;
#pragma unroll
    for (int k = 0; k < 16; k++) {
        af[k] *= inv;
        af[k] += __shfl_xor(af[k], 4);
        af[k] += __shfl_xor(af[k], 8);
    }
    if (l < 4) {
#pragma unroll
        for (int k = 0; k < 16; k++) fsS[wv * 4 + q][l * 16 + k] = af[k];
    }
    __syncthreads();
    // run-pooled graph atomics: 2 wave-uniform groups x 8 nodes
    int t = threadIdx.x;
    if (t < 128) {
        int g = t >> 6;       // nodes g*8 .. g*8+7 (uniform per wave)
        int c = t & 63;
        float bv = b2p[c];
        int curb = batchS[g * 8];
        float run = 0.f;
#pragma unroll
        for (int k = 0; k < 8; k++) {
            int node = g * 8 + k;
            int b = batchS[node];
            float vv = sigmoidf_(0.25f * fsS[node][c] + bv);
            if (b != curb) {
                atomicAdd(&gsum[(size_t)curb * 64 + c], run);
                run = 0.f; curb = b;
            }
            run += vv;
        }
        atomicAdd(&gsum[(size_t)curb * 64 + c], run);
    }
}

// ---------------- final ----------------
__global__ void k_final(const float* __restrict__ gsum, const float* __restrict__ lwp,
                        const float* __restrict__ lb, float* __restrict__ out) {
    int g = blockIdx.x;
    int lane = threadIdx.x;
    float v = gsum[g * 64 + lane] * lwp[lane];
    for (int o = 32; o; o >>= 1) v += __shfl_down(v, o);
    if (lane == 0) out[g] = sigmoidf_(v + lb[0]);
}

// ---------------- launch ----------------
extern "C" void kernel_launch(void* const* d_in, const int* in_sizes, int n_in,
                              void* d_out, int out_size, void* d_ws, size_t ws_size,
                              hipStream_t stream) {
    const int* x   = (const int*)d_in[0];
    const int* ei  = (const int*)d_in[1];
    const int* bat = (const int*)d_in[3];
    const float* e0 = (const float*)d_in[4];
    const float* e1 = (const float*)d_in[5];
    const float* e2 = (const float*)d_in[6];
    const float* e3 = (const float*)d_in[7];
    const float* e4 = (const float*)d_in[8];
    const float* e5 = (const float*)d_in[9];
    const float* W1 = (const float*)d_in[10];
    const float* as1 = (const float*)d_in[11];
    const float* ad1 = (const float*)d_in[12];
    const float* b1 = (const float*)d_in[13];
    const float* W2 = (const float*)d_in[14];
    const float* as2 = (const float*)d_in[15];
    const float* ad2 = (const float*)d_in[16];
    const float* b2 = (const float*)d_in[17];
    const float* lw = (const float*)d_in[18];
    const float* lb = (const float*)d_in[19];
    float* out = (float*)d_out;

    char* base = (char*)d_ws;
    size_t off = 0;
    auto alloc = [&](size_t bytes) {
        size_t o = off;
        off = (off + bytes + 255) & ~(size_t)255;
        return o;
    };
    unsigned char* xw8 = (unsigned char*)(base + alloc((size_t)NN * 256));
    unsigned short* h1b = (unsigned short*)(base + alloc((size_t)NN * 128 * 2));
    float* sdAll = (float*)(base + alloc((size_t)12 * NN * 4));
    float* s1 = sdAll;              // [NN][2]
    float* d1 = sdAll + 2 * NN;     // [NN][2]
    float* s2 = sdAll + 4 * NN;     // [NN][4]
    float* d2 = sdAll + 8 * NN;     // [NN][4]
    float* gsum = (float*)(base + alloc((size_t)GG * 64 * 4));
    int* cnt  = (int*)(base + alloc((size_t)NN * 4));
    int* csrc = (int*)(base + alloc((size_t)NN * 64 * 4));  // 64-slot buckets
    unsigned short* Wt2 = (unsigned short*)(base + alloc((size_t)128 * 256 * 2));
    float* b1p = (float*)(base + alloc((size_t)128 * 4));
    float* b2p = (float*)(base + alloc((size_t)64 * 4));
    float* lwp = (float*)(base + alloc((size_t)64 * 4));
    float* asvp = (float*)(base + alloc((size_t)256 * 4));
    float* advp = (float*)(base + alloc((size_t)256 * 4));
    float* Pp  = (float*)(base + alloc((size_t)50 * 256 * 4));

    const int nb = (NN + 255) / 256;  // 391
    const int nqb = NN / 16;          // 6250 quad-node blocks
    const int nwb = NN / 8;           // 12500 xw1 blocks (8 nodes/block)

    k_zero_prep<<<nb, 256, 0, stream>>>(
        e0, e1, e2, e3, e4, e5, W1, W2, b1, b2, lw, as1, ad1,
        Wt2, b1p, b2p, lwp, asvp, advp, Pp, cnt, csrc, gsum);
    k_histscat_xw1<<<NEB + nwb, 256, 0, stream>>>(ei, cnt, csrc, x, Pp, asvp, advp,
                                                  (unsigned int*)xw8, s1, d1);
    k_agg1<<<nqb, 256, 0, stream>>>(xw8, s1, d1, cnt, csrc, b1p, h1b);

    // layer 2
    {
        dim3 grid(4, (NN + 127) / 128);
        k_gemm2<<<grid, 256, 0, stream>>>(h1b, Wt2, (unsigned int*)xw8,
                                          as2, ad2, s2, d2, NN);
    }
    k_agg2<<<nqb, 256, 0, stream>>>(xw8, s2, d2, cnt, csrc, b2p, bat, gsum);

    // final
    k_final<<<GG, 64, 0, stream>>>(gsum, lwp, lb, out);
}

// Round 21
// 231.794 us; speedup vs baseline: 1.0365x; 1.0365x over previous
//
#include <hip/hip_runtime.h>
#include <hip/hip_bf16.h>

#define NN 100000
#define EE 800000
#define GG 1024
#define PREPB 69    // blocks doing precompute work inside k_zero_prep
#define NEB 1563    // edge blocks (hist-rank, 2 edges/thread)

typedef __attribute__((ext_vector_type(8))) short short8;
typedef __attribute__((ext_vector_type(4))) float floatx4;
typedef __attribute__((ext_vector_type(2))) float floatx2;

__device__ __forceinline__ float sigmoidf_(float v) { return 1.f / (1.f + expf(-v)); }
__device__ __forceinline__ unsigned short f2bf(float f) {
    union { unsigned int i; float f; } x; x.f = f;
    unsigned int r = (x.i + 0x7fff + ((x.i >> 16) & 1)) >> 16;
    return (unsigned short)r;
}
__device__ __forceinline__ unsigned pack2bf(float a, float b) {
    return (unsigned)f2bf(a) | ((unsigned)f2bf(b) << 16);
}
__device__ __forceinline__ float lrelu(float e) { return (e > 0.f) ? e : 0.2f * e; }

// ---- fused init + precompute; also plants self-loop in bucket slot 0 ----
__global__ void k_zero_prep(const float* __restrict__ e0, const float* __restrict__ e1,
                            const float* __restrict__ e2, const float* __restrict__ e3,
                            const float* __restrict__ e4, const float* __restrict__ e5,
                            const float* __restrict__ W1, const float* __restrict__ W2,
                            const float* __restrict__ b1, const float* __restrict__ b2,
                            const float* __restrict__ lw,
                            const float* __restrict__ as1, const float* __restrict__ ad1,
                            unsigned short* __restrict__ Wt2,
                            float* __restrict__ b1p, float* __restrict__ b2p,
                            float* __restrict__ lwp,
                            float* __restrict__ asvp, float* __restrict__ advp,
                            float* __restrict__ Pp,
                            int* __restrict__ cnt, int* __restrict__ csrc,
                            float* __restrict__ gsum) {
    int i = blockIdx.x * 256 + threadIdx.x;
    if (i < NN) {
        cnt[i] = 1;                    // slot 0 reserved for self-loop
        csrc[(size_t)i << 6] = i;      // self-loop
    }
    if (i < GG * 64) gsum[i] = 0.f;
    if (blockIdx.x >= PREPB) return;
    if (i < 4096) {
        int tid = i;
        int l = tid & 63, cf = (tid >> 6) & 15, ks = tid >> 10;
        int kbase = ks * 32 + (l >> 4) * 8;
        int col = cf * 16 + (l & 15);
        unsigned short* o = Wt2 + (size_t)tid * 8;
#pragma unroll
        for (int j = 0; j < 8; j++) {
            int k = kbase + j;   // k in h1-permuted space
            int orig = (k & 64) | (((k & 3) * 16) + ((k & 63) >> 2));
            o[j] = f2bf(W2[(size_t)orig * 256 + col]);
        }
    } else if (i < 4096 + 128) {
        int q = i - 4096;
        int orig = (q & 64) | (((q & 3) * 16) + ((q & 63) >> 2));
        b1p[q] = b1[orig];
    } else if (i < 4224 + 64) {
        int q = i - 4224;
        b2p[q] = b2[(q & 3) * 16 + (q >> 2)];
    } else if (i < 4288 + 64) {
        int q = i - 4288;
        lwp[q] = lw[(q & 3) * 16 + (q >> 2)];
    } else if (i < 4352 + 256) {
        int q = i - 4352;
        int c = (q >> 6) * 64 + (q & 3) * 16 + ((q >> 2) & 15);
        asvp[q] = as1[c];
    } else if (i < 4608 + 256) {
        int q = i - 4608;
        int c = (q >> 6) * 64 + (q & 3) * 16 + ((q >> 2) & 15);
        advp[q] = ad1[c];
    } else if (i < 4864 + 12800) {
        int idx = i - 4864;
        int v = idx >> 8, p = idx & 255;
        int t, r;
        const float* tab;
        if (v < 33)      { t = 0; r = v;      tab = e0; }
        else if (v < 38) { t = 1; r = v - 33; tab = e1; }
        else if (v < 41) { t = 2; r = v - 38; tab = e2; }
        else if (v < 45) { t = 3; r = v - 41; tab = e3; }
        else if (v < 47) { t = 4; r = v - 45; tab = e4; }
        else             { t = 5; r = v - 47; tab = e5; }
        int c = (p >> 6) * 64 + (p & 3) * 16 + ((p >> 2) & 15);
        float acc = 0.f;
        const float* wcol = W1 + (size_t)(t * 64) * 256 + c;
#pragma unroll 8
        for (int kk = 0; kk < 64; kk++) acc += tab[r * 64 + kk] * wcol[(size_t)kk * 256];
        Pp[v * 256 + p] = acc;
    }
}

// ---- fused hist-rank (blocks < NEB, 2 edges/thread) + layer-1 table GEMM ----
// rank IS the bucket slot (no prefix sums needed with 64-slot buckets)
__global__ __launch_bounds__(256) void k_hist_xw1(const int* __restrict__ ei,
                                                  int* __restrict__ cnt,
                                                  int* __restrict__ rank,
                                                  const int* __restrict__ x,
                                                  const float* __restrict__ Pp,
                                                  const float* __restrict__ asvp,
                                                  const float* __restrict__ advp,
                                                  unsigned int* __restrict__ C32,
                                                  float* __restrict__ s1,
                                                  float* __restrict__ d1) {
    if (blockIdx.x < NEB) {
        int e0_ = blockIdx.x * 512 + threadIdx.x;
        int e1_ = e0_ + 256;
        int da = (e0_ < EE) ? ei[EE + e0_] : -1;
        int db = (e1_ < EE) ? ei[EE + e1_] : -1;
        if (da >= 0) rank[e0_] = atomicAdd(&cnt[da], 1);
        if (db >= 0) rank[e1_] = atomicAdd(&cnt[db], 1);
        return;
    }
    int g = threadIdx.x >> 5, l = threadIdx.x & 31;
    int n = (blockIdx.x - NEB) * 8 + g;
    const int2* xr = (const int2*)(x + n * 6);
    int2 xa = xr[0], xb = xr[1], xc = xr[2];
    int v0 = xa.x, v1 = 33 + xa.y, v2 = 38 + xb.x;
    int v3 = 41 + xb.y, v4 = 45 + xc.x, v5 = 47 + xc.y;
    float4 accA = make_float4(0.f, 0.f, 0.f, 0.f);
    float4 accB = make_float4(0.f, 0.f, 0.f, 0.f);
    {
        const float* p0 = Pp + v0 * 256 + l * 8;
        const float* p1 = Pp + v1 * 256 + l * 8;
        const float* p2 = Pp + v2 * 256 + l * 8;
        const float* p3 = Pp + v3 * 256 + l * 8;
        const float* p4 = Pp + v4 * 256 + l * 8;
        const float* p5 = Pp + v5 * 256 + l * 8;
        float4 a0 = *(const float4*)p0, b0 = *(const float4*)(p0 + 4);
        float4 a1 = *(const float4*)p1, b1_ = *(const float4*)(p1 + 4);
        float4 a2 = *(const float4*)p2, b2_ = *(const float4*)(p2 + 4);
        float4 a3 = *(const float4*)p3, b3 = *(const float4*)(p3 + 4);
        float4 a4 = *(const float4*)p4, b4 = *(const float4*)(p4 + 4);
        float4 a5 = *(const float4*)p5, b5 = *(const float4*)(p5 + 4);
        accA.x = a0.x + a1.x + a2.x + a3.x + a4.x + a5.x;
        accA.y = a0.y + a1.y + a2.y + a3.y + a4.y + a5.y;
        accA.z = a0.z + a1.z + a2.z + a3.z + a4.z + a5.z;
        accA.w = a0.w + a1.w + a2.w + a3.w + a4.w + a5.w;
        accB.x = b0.x + b1_.x + b2_.x + b3.x + b4.x + b5.x;
        accB.y = b0.y + b1_.y + b2_.y + b3.y + b4.y + b5.y;
        accB.z = b0.z + b1_.z + b2_.z + b3.z + b4.z + b5.z;
        accB.w = b0.w + b1_.w + b2_.w + b3.w + b4.w + b5.w;
    }
    float4 sA = *(const float4*)(asvp + l * 8), sB = *(const float4*)(asvp + l * 8 + 4);
    float4 dA = *(const float4*)(advp + l * 8), dB = *(const float4*)(advp + l * 8 + 4);
    float ss = accA.x * sA.x + accA.y * sA.y + accA.z * sA.z + accA.w * sA.w
             + accB.x * sB.x + accB.y * sB.y + accB.z * sB.z + accB.w * sB.w;
    float dd = accA.x * dA.x + accA.y * dA.y + accA.z * dA.z + accA.w * dA.w
             + accB.x * dB.x + accB.y * dB.y + accB.z * dB.z + accB.w * dB.w;
#pragma unroll
    for (int o = 1; o <= 8; o <<= 1) {
        ss += __shfl_xor(ss, o);
        dd += __shfl_xor(dd, o);
    }
    if ((l & 15) == 0) {
        int h = l >> 4;
        s1[n * 2 + h] = ss;
        d1[n * 2 + h] = dd;
    }
    int lo0 = __builtin_amdgcn_cvt_pk_fp8_f32(accA.x, accA.y, 0, false);
    unsigned dw0 = (unsigned)__builtin_amdgcn_cvt_pk_fp8_f32(accA.z, accA.w, lo0, true);
    int lo1 = __builtin_amdgcn_cvt_pk_fp8_f32(accB.x, accB.y, 0, false);
    unsigned dw1 = (unsigned)__builtin_amdgcn_cvt_pk_fp8_f32(accB.z, accB.w, lo1, true);
    *(uint2*)(C32 + (size_t)n * 64 + l * 2) = make_uint2(dw0, dw1);
}

// independent-write scatter into buckets using precomputed ranks, 2 edges/thread
__global__ void k_scatter(const int* __restrict__ ei, const int* __restrict__ rank,
                          int* __restrict__ csrc) {
    int e0_ = blockIdx.x * 512 + threadIdx.x;
    int e1_ = e0_ + 256;
    if (e0_ < EE) {
        int s = ei[e0_], d = ei[EE + e0_];
        csrc[((size_t)d << 6) + rank[e0_]] = s;
    }
    if (e1_ < EE) {
        int s = ei[e1_], d = ei[EE + e1_];
        csrc[((size_t)d << 6) + rank[e1_]] = s;
    }
}

// ------- layer-2 bf16 MFMA GEMM -> fp8 (permuted dword stores) + plain s/d ----
__global__ __launch_bounds__(256) void k_gemm2(const unsigned short* __restrict__ Abf,
                                               const unsigned short* __restrict__ Wt,
                                               unsigned int* __restrict__ C32,
                                               const float* __restrict__ asv,
                                               const float* __restrict__ adv,
                                               float* __restrict__ sOut,
                                               float* __restrict__ dOut, int M) {
    __shared__ __align__(16) unsigned short As[128 * 40];
    __shared__ __align__(16) unsigned short Bs[4 * 64 * 8];
    int tid = threadIdx.x;
    int rowBase = blockIdx.y * 128;
    int colBase = blockIdx.x * 64;
    int l = tid & 63, w = tid >> 6;
    int strip = w * 32;
    floatx4 acc[2][4] = {};

    for (int ks = 0; ks < 4; ks++) {
        {
            int r = tid >> 1, half = tid & 1;
            int row = rowBase + r;
            uint4 v0 = {0, 0, 0, 0}, v1 = {0, 0, 0, 0};
            if (row < M) {
                const unsigned short* src = Abf + (size_t)row * 128 + ks * 32 + half * 16;
                v0 = *(const uint4*)src;
                v1 = *(const uint4*)(src + 8);
            }
            uint4* dst = (uint4*)&As[r * 40 + half * 16];
            dst[0] = v0; dst[1] = v1;
        }
        {
            const unsigned short* wsrc =
                Wt + ((size_t)(ks * 16 + (colBase >> 4)) * 64) * 8 + tid * 8;
            *(uint4*)&Bs[tid * 8] = *(const uint4*)wsrc;
        }
        __syncthreads();
        short8 a0 = *(const short8*)&As[(strip + (l & 15)) * 40 + (l >> 4) * 8];
        short8 a1 = *(const short8*)&As[(strip + 16 + (l & 15)) * 40 + (l >> 4) * 8];
        const short8* bp = (const short8*)&Bs[0];
#pragma unroll
        for (int cf = 0; cf < 4; cf++) {
            short8 b = bp[cf * 64 + l];
            acc[0][cf] = __builtin_amdgcn_mfma_f32_16x16x32_bf16(a0, b, acc[0][cf], 0, 0, 0);
            acc[1][cf] = __builtin_amdgcn_mfma_f32_16x16x32_bf16(a1, b, acc[1][cf], 0, 0, 0);
        }
        __syncthreads();
    }
    float as_[4], ad_[4];
#pragma unroll
    for (int cf = 0; cf < 4; cf++) {
        int col = colBase + cf * 16 + (l & 15);
        as_[cf] = asv[col];
        ad_[cf] = adv[col];
    }
    float ps[8], pd[8];
    unsigned dw[8];
#pragma unroll
    for (int rf = 0; rf < 2; rf++)
#pragma unroll
        for (int i = 0; i < 4; i++) {
            int idx = rf * 4 + i;
            float a0 = acc[rf][0][i], a1 = acc[rf][1][i];
            float a2 = acc[rf][2][i], a3 = acc[rf][3][i];
            ps[idx] = a0 * as_[0] + a1 * as_[1] + a2 * as_[2] + a3 * as_[3];
            pd[idx] = a0 * ad_[0] + a1 * ad_[1] + a2 * ad_[2] + a3 * ad_[3];
            int lo = __builtin_amdgcn_cvt_pk_fp8_f32(a0, a1, 0, false);
            dw[idx] = (unsigned)__builtin_amdgcn_cvt_pk_fp8_f32(a2, a3, lo, true);
        }
#pragma unroll
    for (int rf = 0; rf < 2; rf++)
#pragma unroll
        for (int i = 0; i < 4; i++) {
            int row = rowBase + strip + rf * 16 + (l >> 4) * 4 + i;
            if (row < M) C32[(size_t)row * 64 + (colBase >> 2) + (l & 15)] = dw[rf * 4 + i];
        }
#pragma unroll
    for (int k = 0; k < 8; k++)
#pragma unroll
        for (int o = 8; o; o >>= 1) {
            ps[k] += __shfl_xor(ps[k], o);
            pd[k] += __shfl_xor(pd[k], o);
        }
    if ((l & 15) == 0) {
        int head = colBase >> 6;   // H=4, one block.x per head -> plain store
#pragma unroll
        for (int rf = 0; rf < 2; rf++)
#pragma unroll
            for (int i = 0; i < 4; i++) {
                int row = rowBase + strip + rf * 16 + (l >> 4) * 4 + i;
                if (row < M) {
                    sOut[row * 4 + head] = ps[rf * 4 + i];
                    dOut[row * 4 + head] = pd[rf * 4 + i];
                }
            }
    }
}

// ------- layer-1 aggregation: bucket CSR, no-max softmax, deferred denom -------
__global__ __launch_bounds__(256) void k_agg1(const unsigned char* __restrict__ xw8,
                                              const float* __restrict__ s,
                                              const float* __restrict__ dvec,
                                              const int* __restrict__ cnt,
                                              const int* __restrict__ csrc,
                                              const float* __restrict__ b1p,
                                              unsigned short* __restrict__ h1b) {
    __shared__ int snS[4][4][16];
    __shared__ float wS[4][4][2][16];
    int wv = threadIdx.x >> 6, lane = threadIdx.x & 63;
    int q = lane >> 4, l = lane & 15;
    int hh = l >> 3;
    int n = blockIdx.x * 16 + wv * 4 + q;
    int start = n << 6;
    int deg = cnt[n];
    float2 dn = *(const float2*)(dvec + n * 2);
    floatx2 acc[8] = {};
    float ws0, ws1;

    auto macc = [&](const uint4& v, float wgt) {
        floatx2 p;
        p = __builtin_amdgcn_cvt_pk_f32_fp8(v.x, false); acc[0] += wgt * p;
        p = __builtin_amdgcn_cvt_pk_f32_fp8(v.x, true);  acc[1] += wgt * p;
        p = __builtin_amdgcn_cvt_pk_f32_fp8(v.y, false); acc[2] += wgt * p;
        p = __builtin_amdgcn_cvt_pk_f32_fp8(v.y, true);  acc[3] += wgt * p;
        p = __builtin_amdgcn_cvt_pk_f32_fp8(v.z, false); acc[4] += wgt * p;
        p = __builtin_amdgcn_cvt_pk_f32_fp8(v.z, true);  acc[5] += wgt * p;
        p = __builtin_amdgcn_cvt_pk_f32_fp8(v.w, false); acc[6] += wgt * p;
        p = __builtin_amdgcn_cvt_pk_f32_fp8(v.w, true);  acc[7] += wgt * p;
    };
    auto run_chunk = [&](int cnt_) {
        int j = 0;
        for (; j + 2 <= cnt_; j += 2) {
            int sa = snS[wv][q][j], sb = snS[wv][q][j + 1];
            uint4 va = *(const uint4*)(xw8 + (size_t)sa * 256 + l * 16);
            uint4 vb = *(const uint4*)(xw8 + (size_t)sb * 256 + l * 16);
            float wa = wS[wv][q][hh][j], wb = wS[wv][q][hh][j + 1];
            macc(va, wa); macc(vb, wb);
        }
        if (j < cnt_) {
            int sa = snS[wv][q][j];
            uint4 va = *(const uint4*)(xw8 + (size_t)sa * 256 + l * 16);
            macc(va, wS[wv][q][hh][j]);
        }
    };

    if (deg <= 16) {
        int sn = 0; float w0 = 0.f, w1 = 0.f;
        if (l < deg) {
            sn = csrc[start + l];
            float2 sv = *(const float2*)(s + sn * 2);
            w0 = __expf(lrelu(sv.x + dn.x));
            w1 = __expf(lrelu(sv.y + dn.y));
        }
        snS[wv][q][l] = sn; wS[wv][q][0][l] = w0; wS[wv][q][1][l] = w1;
        run_chunk(deg);
        ws0 = w0; ws1 = w1;
#pragma unroll
        for (int o = 8; o; o >>= 1) {
            ws0 += __shfl_xor(ws0, o);
            ws1 += __shfl_xor(ws1, o);
        }
    } else {
        float wa0 = 0.f, wa1 = 0.f;
        int end = start + deg;
        for (int cb = start; cb < end; cb += 16) {
            int cnt_ = min(16, end - cb);
            int sn = 0; float w0 = 0.f, w1 = 0.f;
            if (l < cnt_) {
                sn = csrc[cb + l];
                float2 sv = *(const float2*)(s + sn * 2);
                w0 = __expf(lrelu(sv.x + dn.x));
                w1 = __expf(lrelu(sv.y + dn.y));
            }
            wa0 += w0; wa1 += w1;
            snS[wv][q][l] = sn; wS[wv][q][0][l] = w0; wS[wv][q][1][l] = w1;
            run_chunk(cnt_);
        }
        ws0 = wa0; ws1 = wa1;
#pragma unroll
        for (int o = 8; o; o >>= 1) {
            ws0 += __shfl_xor(ws0, o);
            ws1 += __shfl_xor(ws1, o);
        }
    }
    float inv = 1.f / ((hh ? ws1 : ws0) + 1e-16f);
    float* af = (float*)acc;
    float hm[16];
#pragma unroll
    for (int k = 0; k < 16; k++) {
        af[k] *= inv;
        hm[k] = 0.5f * (af[k] + __shfl_xor(af[k], 8));  // head mean
    }
    if (l < 8) {
        const float* bb = b1p + l * 16;
        unsigned st[8];
#pragma unroll
        for (int k2 = 0; k2 < 8; k2++)
            st[k2] = pack2bf(sigmoidf_(hm[2 * k2] + bb[2 * k2]),
                             sigmoidf_(hm[2 * k2 + 1] + bb[2 * k2 + 1]));
        uint4* dst = (uint4*)(h1b + (size_t)n * 128 + l * 16);
        dst[0] = make_uint4(st[0], st[1], st[2], st[3]);
        dst[1] = make_uint4(st[4], st[5], st[6], st[7]);
    }
}

// ------- layer-2 aggregation: bucket CSR + run-pooled graph atomics -------
__global__ __launch_bounds__(256) void k_agg2(const unsigned char* __restrict__ xw8,
                                              const float* __restrict__ s,
                                              const float* __restrict__ dvec,
                                              const int* __restrict__ cnt,
                                              const int* __restrict__ csrc,
                                              const float* __restrict__ b2p,
                                              const int* __restrict__ batch,
                                              float* __restrict__ gsum) {
    __shared__ int snS[4][4][16];
    __shared__ float wS[4][4][4][16];
    __shared__ float fsS[16][64];
    __shared__ int batchS[16];
    int wv = threadIdx.x >> 6, lane = threadIdx.x & 63;
    int q = lane >> 4, l = lane & 15;
    int hh = l >> 2;
    int n = blockIdx.x * 16 + wv * 4 + q;
    if (threadIdx.x < 16) batchS[threadIdx.x] = batch[blockIdx.x * 16 + threadIdx.x];
    int start = n << 6;
    int deg = cnt[n];
    float4 dn = *(const float4*)(dvec + n * 4);
    floatx2 acc[8] = {};
    float ws0, ws1, ws2, ws3;

    auto macc = [&](const uint4& v, float wgt) {
        floatx2 p;
        p = __builtin_amdgcn_cvt_pk_f32_fp8(v.x, false); acc[0] += wgt * p;
        p = __builtin_amdgcn_cvt_pk_f32_fp8(v.x, true);  acc[1] += wgt * p;
        p = __builtin_amdgcn_cvt_pk_f32_fp8(v.y, false); acc[2] += wgt * p;
        p = __builtin_amdgcn_cvt_pk_f32_fp8(v.y, true);  acc[3] += wgt * p;
        p = __builtin_amdgcn_cvt_pk_f32_fp8(v.z, false); acc[4] += wgt * p;
        p = __builtin_amdgcn_cvt_pk_f32_fp8(v.z, true);  acc[5] += wgt * p;
        p = __builtin_amdgcn_cvt_pk_f32_fp8(v.w, false); acc[6] += wgt * p;
        p = __builtin_amdgcn_cvt_pk_f32_fp8(v.w, true);  acc[7] += wgt * p;
    };
    auto run_chunk = [&](int cnt_) {
        int j = 0;
        for (; j + 2 <= cnt_; j += 2) {
            int sa = snS[wv][q][j], sb = snS[wv][q][j + 1];
            uint4 va = *(const uint4*)(xw8 + (size_t)sa * 256 + l * 16);
            uint4 vb = *(const uint4*)(xw8 + (size_t)sb * 256 + l * 16);
            float wa = wS[wv][q][hh][j], wb = wS[wv][q][hh][j + 1];
            macc(va, wa); macc(vb, wb);
        }
        if (j < cnt_) {
            int sa = snS[wv][q][j];
            uint4 va = *(const uint4*)(xw8 + (size_t)sa * 256 + l * 16);
            macc(va, wS[wv][q][hh][j]);
        }
    };

    if (deg <= 16) {
        int sn = 0;
        float w0 = 0.f, w1 = 0.f, w2 = 0.f, w3 = 0.f;
        if (l < deg) {
            sn = csrc[start + l];
            float4 sv = *(const float4*)(s + sn * 4);
            w0 = __expf(lrelu(sv.x + dn.x));
            w1 = __expf(lrelu(sv.y + dn.y));
            w2 = __expf(lrelu(sv.z + dn.z));
            w3 = __expf(lrelu(sv.w + dn.w));
        }
        snS[wv][q][l] = sn;
        wS[wv][q][0][l] = w0; wS[wv][q][1][l] = w1;
        wS[wv][q][2][l] = w2; wS[wv][q][3][l] = w3;
        run_chunk(deg);
        ws0 = w0; ws1 = w1; ws2 = w2; ws3 = w3;
#pragma unroll
        for (int o = 8; o; o >>= 1) {
            ws0 += __shfl_xor(ws0, o); ws1 += __shfl_xor(ws1, o);
            ws2 += __shfl_xor(ws2, o); ws3 += __shfl_xor(ws3, o);
        }
    } else {
        float wa0 = 0.f, wa1 = 0.f, wa2 = 0.f, wa3 = 0.f;
        int end = start + deg;
        for (int cb = start; cb < end; cb += 16) {
            int cnt_ = min(16, end - cb);
            int sn = 0; float w0 = 0.f, w1 = 0.f, w2 = 0.f, w3 = 0.f;
            if (l < cnt_) {
                sn = csrc[cb + l];
                float4 sv = *(const float4*)(s + sn * 4);
                w0 = __expf(lrelu(sv.x + dn.x));
                w1 = __expf(lrelu(sv.y + dn.y));
                w2 = __expf(lrelu(sv.z + dn.z));
                w3 = __expf(lrelu(sv.w + dn.w));
            }
            wa0 += w0; wa1 += w1; wa2 += w2; wa3 += w3;
            snS[wv][q][l] = sn;
            wS[wv][q][0][l] = w0; wS[wv][q][1][l] = w1;
            wS[wv][q][2][l] = w2; wS[wv][q][3][l] = w3;
            run_chunk(cnt_);
        }
        ws0 = wa0; ws1 = wa1; ws2 = wa2; ws3 = wa3;
#pragma unroll
        for (int o = 8; o; o >>= 1) {
            ws0 += __shfl_xor(ws0, o); ws1 += __shfl_xor(ws1, o);
            ws2 += __shfl_xor(ws2, o); ws3 += __shfl_xor(ws3, o);
        }
    }
    float wsel = (hh & 2) ? ((hh & 1) ? ws3 : ws2) : ((hh & 1) ? ws1 : ws0);
    float inv = 1.f / (wsel + 1e-16f);
    float* af = (float*)acc;
#pragma unroll
    for (int k = 0; k < 16; k++) {
        af[k] *= inv;
        af[k] += __shfl_xor(af[k], 4);
        af[k] += __shfl_xor(af[k], 8);
    }
    if (l < 4) {
#pragma unroll
        for (int k = 0; k < 16; k++) fsS[wv * 4 + q][l * 16 + k] = af[k];
    }
    __syncthreads();
    // run-pooled graph atomics: 2 wave-uniform groups x 8 nodes
    int t = threadIdx.x;
    if (t < 128) {
        int g = t >> 6;       // nodes g*8 .. g*8+7 (uniform per wave)
        int c = t & 63;
        float bv = b2p[c];
        int curb = batchS[g * 8];
        float run = 0.f;
#pragma unroll
        for (int k = 0; k < 8; k++) {
            int node = g * 8 + k;
            int b = batchS[node];
            float vv = sigmoidf_(0.25f * fsS[node][c] + bv);
            if (b != curb) {
                atomicAdd(&gsum[(size_t)curb * 64 + c], run);
                run = 0.f; curb = b;
            }
            run += vv;
        }
        atomicAdd(&gsum[(size_t)curb * 64 + c], run);
    }
}

// ---------------- final ----------------
__global__ void k_final(const float* __restrict__ gsum, const float* __restrict__ lwp,
                        const float* __restrict__ lb, float* __restrict__ out) {
    int g = blockIdx.x;
    int lane = threadIdx.x;
    float v = gsum[g * 64 + lane] * lwp[lane];
    for (int o = 32; o; o >>= 1) v += __shfl_down(v, o);
    if (lane == 0) out[g] = sigmoidf_(v + lb[0]);
}

// ---------------- launch ----------------
extern "C" void kernel_launch(void* const* d_in, const int* in_sizes, int n_in,
                              void* d_out, int out_size, void* d_ws, size_t ws_size,
                              hipStream_t stream) {
    const int* x   = (const int*)d_in[0];
    const int* ei  = (const int*)d_in[1];
    const int* bat = (const int*)d_in[3];
    const float* e0 = (const float*)d_in[4];
    const float* e1 = (const float*)d_in[5];
    const float* e2 = (const float*)d_in[6];
    const float* e3 = (const float*)d_in[7];
    const float* e4 = (const float*)d_in[8];
    const float* e5 = (const float*)d_in[9];
    const float* W1 = (const float*)d_in[10];
    const float* as1 = (const float*)d_in[11];
    const float* ad1 = (const float*)d_in[12];
    const float* b1 = (const float*)d_in[13];
    const float* W2 = (const float*)d_in[14];
    const float* as2 = (const float*)d_in[15];
    const float* ad2 = (const float*)d_in[16];
    const float* b2 = (const float*)d_in[17];
    const float* lw = (const float*)d_in[18];
    const float* lb = (const float*)d_in[19];
    float* out = (float*)d_out;

    char* base = (char*)d_ws;
    size_t off = 0;
    auto alloc = [&](size_t bytes) {
        size_t o = off;
        off = (off + bytes + 255) & ~(size_t)255;
        return o;
    };
    unsigned char* xw8 = (unsigned char*)(base + alloc((size_t)NN * 256));
    unsigned short* h1b = (unsigned short*)(base + alloc((size_t)NN * 128 * 2));
    float* sdAll = (float*)(base + alloc((size_t)12 * NN * 4));
    float* s1 = sdAll;              // [NN][2]
    float* d1 = sdAll + 2 * NN;     // [NN][2]
    float* s2 = sdAll + 4 * NN;     // [NN][4]
    float* d2 = sdAll + 8 * NN;     // [NN][4]
    float* gsum = (float*)(base + alloc((size_t)GG * 64 * 4));
    int* cnt  = (int*)(base + alloc((size_t)NN * 4));
    int* rank = (int*)(base + alloc((size_t)EE * 4));
    int* csrc = (int*)(base + alloc((size_t)NN * 64 * 4));  // 64-slot buckets
    unsigned short* Wt2 = (unsigned short*)(base + alloc((size_t)128 * 256 * 2));
    float* b1p = (float*)(base + alloc((size_t)128 * 4));
    float* b2p = (float*)(base + alloc((size_t)64 * 4));
    float* lwp = (float*)(base + alloc((size_t)64 * 4));
    float* asvp = (float*)(base + alloc((size_t)256 * 4));
    float* advp = (float*)(base + alloc((size_t)256 * 4));
    float* Pp  = (float*)(base + alloc((size_t)50 * 256 * 4));

    const int nb = (NN + 255) / 256;  // 391
    const int nqb = NN / 16;          // 6250 quad-node blocks
    const int nwb = NN / 8;           // 12500 xw1 blocks (8 nodes/block)

    k_zero_prep<<<nb, 256, 0, stream>>>(
        e0, e1, e2, e3, e4, e5, W1, W2, b1, b2, lw, as1, ad1,
        Wt2, b1p, b2p, lwp, asvp, advp, Pp, cnt, csrc, gsum);
    k_hist_xw1<<<NEB + nwb, 256, 0, stream>>>(ei, cnt, rank, x, Pp, asvp, advp,
                                              (unsigned int*)xw8, s1, d1);
    k_scatter<<<NEB, 256, 0, stream>>>(ei, rank, csrc);

    k_agg1<<<nqb, 256, 0, stream>>>(xw8, s1, d1, cnt, csrc, b1p, h1b);

    // layer 2
    {
        dim3 grid(4, (NN + 127) / 128);
        k_gemm2<<<grid, 256, 0, stream>>>(h1b, Wt2, (unsigned int*)xw8,
                                          as2, ad2, s2, d2, NN);
    }
    k_agg2<<<nqb, 256, 0, stream>>>(xw8, s2, d2, cnt, csrc, b2p, bat, gsum);

    // final
    k_final<<<GG, 64, 0, stream>>>(gsum, lwp, lb, out);
}